// Round 11
// baseline (84.989 us; speedup 1.0000x reference)
//
#include <hip/hip_runtime.h>
#include <hip/hip_bf16.h>
#include <math.h>

#define EPSB 1e-5f

constexpr int NN = 32, CIN = 256, HH = 56, WW = 56, HW = HH * WW; // 3136
constexpr int CMID = 16, NB = 4, CBOX = 64, COUT = 256;

typedef __attribute__((ext_vector_type(8))) short short8;
typedef __attribute__((ext_vector_type(4))) float f32x4;

// workspace offsets (in float units)
constexpr size_t WS_OUT1B = 0;                                     // N*16*HW bf16
constexpr size_t WS_OUT2B = WS_OUT1B + (size_t)NN * CMID * HW / 2; // N*64*HW bf16

// conv1 (256->16) + BN1 + ReLU via bf16 MFMA.
// Block: 256 thr (4 waves), tile = 64 px x 256 ci -> 16 c x 64 px.
__global__ __launch_bounds__(256) void k1(const float* __restrict__ x,
                                          const float* __restrict__ w1,
                                          const float* __restrict__ g1,
                                          const float* __restrict__ b1,
                                          const float* __restrict__ m1,
                                          const float* __restrict__ v1,
                                          __hip_bfloat16* __restrict__ out1b) {
  __shared__ __hip_bfloat16 Xb[64][264]; // [px][ci], 528B rows
  __shared__ __hip_bfloat16 Wb[16][264]; // [c][ci] folded w1*inv1
  int bid = blockIdx.x;                  // NN*49
  int n = bid / 49, hwb = (bid % 49) * 64;
  int tid = threadIdx.x;
  int l = tid & 63, w = tid >> 6;

  // stage Wb: thread t -> c = t>>4, k-range = (t&15)*16 .. +16
  {
    int c = tid >> 4, kb = (tid & 15) * 16;
    float inv = g1[c] / sqrtf(v1[c] + EPSB);
    const float* wp = w1 + c * CIN + kb;
#pragma unroll
    for (int j = 0; j < 16; ++j)
      Wb[c][kb + j] = __float2bfloat16(wp[j] * inv);
  }

  // stage Xb transposed: thread t -> px quad (t&15)*4, ci pair base (t>>4)*2
  {
    const float* xb = x + (size_t)n * CIN * HW + hwb;
    int pxq = (tid & 15) * 4;
    int cio = (tid >> 4) * 2;
#pragma unroll
    for (int p = 0; p < 8; ++p) {
      int ci = p * 32 + cio;
      f32x4 a = *reinterpret_cast<const f32x4*>(xb + (size_t)ci * HW + pxq);
      f32x4 b = *reinterpret_cast<const f32x4*>(xb + (size_t)(ci + 1) * HW + pxq);
#pragma unroll
      for (int j = 0; j < 4; ++j) {
        unsigned lo = (unsigned)__bfloat16_as_ushort(__float2bfloat16(a[j]));
        unsigned hi = (unsigned)__bfloat16_as_ushort(__float2bfloat16(b[j]));
        *reinterpret_cast<unsigned*>(&Xb[pxq + j][ci]) = lo | (hi << 16);
      }
    }
  }
  __syncthreads();

  // MFMA: A = Wb [c][k], B = Xb [k][px] (frag reads from [px][k] rows)
  int pix = 16 * w + (l & 15);
  f32x4 acc = (f32x4)(0.f);
#pragma unroll
  for (int kk = 0; kk < 8; ++kk) {
    int k0 = kk * 32 + (l >> 4) * 8;
    short8 afr = *reinterpret_cast<const short8*>(&Wb[l & 15][k0]);
    short8 bfr = *reinterpret_cast<const short8*>(&Xb[pix][k0]);
    acc = __builtin_amdgcn_mfma_f32_16x16x32_bf16(afr, bfr, acc, 0, 0, 0);
  }

  // epilogue: D row = c = (l>>4)*4 + j, col = pix  (bf16 stores)
#pragma unroll
  for (int j = 0; j < 4; ++j) {
    int c = (l >> 4) * 4 + j;
    float inv = g1[c] / sqrtf(v1[c] + EPSB);
    float val = acc[j] + (b1[c] - m1[c] * inv);
    out1b[((size_t)n * CMID + c) * HW + hwb + pix] = __float2bfloat16(fmaxf(val, 0.f));
  }
}

// 8-byte LDS load at 4-byte alignment -> ds_read2_b32 (1 LDS instr)
struct __attribute__((packed, aligned(4))) fpair { float lo, hi; };

__device__ __forceinline__ float bilin(const float* __restrict__ sI, float y, float x) {
  int iy = min((int)y, 55);
  int ix = min((int)x, 55);
  float ty = y - (float)iy;
  float tx = x - (float)ix;
  const float* r = sI + iy * 57 + ix;
  fpair ab = *reinterpret_cast<const fpair*>(r);       // a=r[0], b=r[1]
  fpair cd = *reinterpret_cast<const fpair*>(r + 57);  // c=r[57], d=r[58]
  float g1v = ab.lo * (1.f - ty) + cd.lo * ty;
  float g2v = ab.hi * (1.f - ty) + cd.hi * ty;
  return g1v * (1.f - tx) + g2v * tx;
}

// integral image (wave-parallel scans) + 4 boxes + BN2 + ReLU -> bf16.
__global__ __launch_bounds__(512) void k2(
    const __hip_bfloat16* __restrict__ out1b,
    const float* __restrict__ y_min, const float* __restrict__ y_max,
    const float* __restrict__ x_min, const float* __restrict__ x_max,
    const float* __restrict__ g2, const float* __restrict__ b2,
    const float* __restrict__ m2, const float* __restrict__ v2,
    __hip_bfloat16* __restrict__ out2b) {
  __shared__ float sI[57 * 57];
  int bid = blockIdx.x;            // NN*CMID = 512
  int n = bid >> 4, c = bid & 15;
  int tid = threadIdx.x;
  int lane = tid & 63, w = tid >> 6; // 8 waves

  if (tid < 57) { sI[tid] = 0.f; sI[tid * 57] = 0.f; }
  const __hip_bfloat16* src = out1b + ((size_t)n * CMID + c) * HW;
  if (tid < HW / 8) { // 392 vector loads of 8 px (56%8==0 -> same row)
    int p = tid * 8;
    int h = p / 56, wq = p - h * 56;
    short8 d = ((const short8*)src)[tid];
    const __hip_bfloat16* dp = (const __hip_bfloat16*)&d;
    float* dst = &sI[(h + 1) * 57 + wq + 1];
#pragma unroll
    for (int j = 0; j < 8; ++j) dst[j] = __bfloat162float(dp[j]);
  }
  __syncthreads();

  for (int r = w; r < 56; r += 8) {
    float* row = &sI[(r + 1) * 57 + 1];
    float vv = (lane < 56) ? row[lane] : 0.f;
#pragma unroll
    for (int d = 1; d < 64; d <<= 1) {
      float o = __shfl_up(vv, d, 64);
      if (lane >= d) vv += o;
    }
    if (lane < 56) row[lane] = vv;
  }
  __syncthreads();
  for (int cc = w; cc < 56; cc += 8) {
    float* col = &sI[57 + cc + 1];
    float vv = (lane < 56) ? col[lane * 57] : 0.f;
#pragma unroll
    for (int d = 1; d < 64; d <<= 1) {
      float o = __shfl_up(vv, d, 64);
      if (lane >= d) vv += o;
    }
    if (lane < 56) col[lane * 57] = vv;
  }
  __syncthreads();

  float pymn[NB], pymx[NB], pxmn[NB], pxmx[NB], pinv[NB], pbi[NB], prar[NB];
#pragma unroll
  for (int b = 0; b < NB; ++b) {
    int cb = c * NB + b;
    pymn[b] = y_min[cb]; pymx[b] = y_max[cb];
    pxmn[b] = x_min[cb]; pxmx[b] = x_max[cb];
    float inv = g2[cb] / sqrtf(v2[cb] + EPSB);
    pinv[b] = inv;
    pbi[b] = b2[cb] - m2[cb] * inv;
    prar[b] = 1.f / ((pymx[b] - pymn[b] + 1.f) * (pxmx[b] - pxmn[b] + 1.f));
  }
  __hip_bfloat16* dst0 = out2b + ((size_t)n * CBOX + c * NB) * HW;

  for (int p = tid; p < HW; p += 512) {
    int h = p / 56, wq = p - h * 56;
    float fh = (float)h, fw = (float)wq;
#pragma unroll
    for (int b = 0; b < NB; ++b) {
      float y1 = fminf(fmaxf(fh + pymn[b], 0.f), 56.f);
      float y2 = fminf(fmaxf(fh + pymx[b] + 1.f, 0.f), 56.f);
      float x1 = fminf(fmaxf(fw + pxmn[b], 0.f), 56.f);
      float x2 = fminf(fmaxf(fw + pxmx[b] + 1.f, 0.f), 56.f);
      float S = bilin(sI, y2, x2) - bilin(sI, y2, x1) - bilin(sI, y1, x2) + bilin(sI, y1, x1);
      float val = S * prar[b] * pinv[b] + pbi[b];
      dst0[(size_t)b * HW + p] = __float2bfloat16(fmaxf(val, 0.f));
    }
  }
}

// conv3 (64->256) via bf16 MFMA + BN3 + residual + ReLU.
// Operand order: mfma(T_tile, w3_tile) -> D rows = pixels -> f32x4 epilogue.
__global__ __launch_bounds__(512) void k3(
    const __hip_bfloat16* __restrict__ out2b,
    const float* __restrict__ w3,
    const float* __restrict__ g3, const float* __restrict__ b3,
    const float* __restrict__ m3, const float* __restrict__ v3,
    const float* __restrict__ x, float* __restrict__ out) {
  __shared__ __hip_bfloat16 T[64][72]; // [pix][k], 144B rows
  int bid = blockIdx.x;                // NN*49
  int n = bid / 49, hwb = (bid % 49) * 64;
  int tid = threadIdx.x;
  int l = tid & 63, w = tid >> 6;

  {
    const __hip_bfloat16* srcp = out2b + ((size_t)n * CBOX + l) * HW + hwb + w * 8;
    short8 v = *reinterpret_cast<const short8*>(srcp);
    const __hip_bfloat16* vp = (const __hip_bfloat16*)&v;
#pragma unroll
    for (int i = 0; i < 8; ++i) T[w * 8 + i][l] = vp[i];
  }

  // w3 frags (B operand): lane l holds w3[o = w*32+ot*16+(l&15)][k0+(l>>4)*8+j]
  short8 wfrag[2][2];
#pragma unroll
  for (int ot = 0; ot < 2; ++ot)
#pragma unroll
    for (int kh = 0; kh < 2; ++kh) {
      int o = w * 32 + ot * 16 + (l & 15);
      int k0 = kh * 32 + (l >> 4) * 8;
      const float* wp = w3 + o * CBOX + k0;
      union { short8 s; __hip_bfloat16 h[8]; } u;
#pragma unroll
      for (int j = 0; j < 8; ++j) u.h[j] = __float2bfloat16(wp[j]);
      wfrag[ot][kh] = u.s;
    }

  __syncthreads();

  // T frags (A operand): lane l holds T[px = pt*16+(l&15)][k0+(l>>4)*8+j]
  short8 tfrag[4][2];
#pragma unroll
  for (int pt = 0; pt < 4; ++pt)
#pragma unroll
    for (int kh = 0; kh < 2; ++kh) {
      int pix = pt * 16 + (l & 15);
      int k0 = kh * 32 + (l >> 4) * 8;
      tfrag[pt][kh] = *reinterpret_cast<const short8*>(&T[pix][k0]);
    }

  f32x4 acc[4][2];
#pragma unroll
  for (int pt = 0; pt < 4; ++pt)
#pragma unroll
    for (int ot = 0; ot < 2; ++ot) acc[pt][ot] = (f32x4)(0.f);

#pragma unroll
  for (int pt = 0; pt < 4; ++pt)
#pragma unroll
    for (int ot = 0; ot < 2; ++ot) {
      acc[pt][ot] = __builtin_amdgcn_mfma_f32_16x16x32_bf16(
          tfrag[pt][0], wfrag[ot][0], acc[pt][ot], 0, 0, 0);
      acc[pt][ot] = __builtin_amdgcn_mfma_f32_16x16x32_bf16(
          tfrag[pt][1], wfrag[ot][1], acc[pt][ot], 0, 0, 0);
    }

  // epilogue: D row = px = pt*16+(l>>4)*4+j, col = o = w*32+ot*16+(l&15)
  size_t nbase = (size_t)n * COUT * HW + hwb;
#pragma unroll
  for (int ot = 0; ot < 2; ++ot) {
    int o = w * 32 + ot * 16 + (l & 15);
    float iv = g3[o] / sqrtf(v3[o] + EPSB);
    float bb = b3[o] - m3[o] * iv;
    size_t rowbase = nbase + (size_t)o * HW;
#pragma unroll
    for (int pt = 0; pt < 4; ++pt) {
      int px0 = pt * 16 + (l >> 4) * 4;
      f32x4 xv = *reinterpret_cast<const f32x4*>(x + rowbase + px0);
      f32x4 r;
#pragma unroll
      for (int j = 0; j < 4; ++j)
        r[j] = fmaxf(acc[pt][ot][j] * iv + bb + xv[j], 0.f);
      *reinterpret_cast<f32x4*>(out + rowbase + px0) = r;
    }
  }
}

extern "C" void kernel_launch(void* const* d_in, const int* in_sizes, int n_in,
                              void* d_out, int out_size, void* d_ws, size_t ws_size,
                              hipStream_t stream) {
  const float* x   = (const float*)d_in[0];
  const float* w1  = (const float*)d_in[1];
  const float* g1  = (const float*)d_in[2];
  const float* b1  = (const float*)d_in[3];
  const float* m1  = (const float*)d_in[4];
  const float* v1  = (const float*)d_in[5];
  const float* ymn = (const float*)d_in[6];
  const float* ymx = (const float*)d_in[7];
  const float* xmn = (const float*)d_in[8];
  const float* xmx = (const float*)d_in[9];
  const float* g2  = (const float*)d_in[10];
  const float* b2  = (const float*)d_in[11];
  const float* m2  = (const float*)d_in[12];
  const float* v2  = (const float*)d_in[13];
  const float* w3  = (const float*)d_in[14];
  const float* g3  = (const float*)d_in[15];
  const float* b3  = (const float*)d_in[16];
  const float* m3  = (const float*)d_in[17];
  const float* v3  = (const float*)d_in[18];

  float* ws  = (float*)d_ws;
  float* out = (float*)d_out;
  __hip_bfloat16* out1b = (__hip_bfloat16*)(ws + WS_OUT1B);
  __hip_bfloat16* out2b = (__hip_bfloat16*)(ws + WS_OUT2B);

  k1<<<NN * 49, 256, 0, stream>>>(x, w1, g1, b1, m1, v1, out1b);
  k2<<<NN * CMID, 512, 0, stream>>>(out1b, ymn, ymx, xmn, xmx,
                                    g2, b2, m2, v2, out2b);
  k3<<<NN * 49, 512, 0, stream>>>(out2b, w3, g3, b3, m3, v3, x, out);
}

// Round 12
// 80.673 us; speedup vs baseline: 1.0535x; 1.0535x over previous
//
#include <hip/hip_runtime.h>
#include <hip/hip_bf16.h>
#include <math.h>

#define EPSB 1e-5f

constexpr int NN = 32, CIN = 256, HH = 56, WW = 56, HW = HH * WW; // 3136
constexpr int CMID = 16, NB = 4, CBOX = 64, COUT = 256;

typedef __attribute__((ext_vector_type(8))) short short8;
typedef __attribute__((ext_vector_type(4))) float f32x4;

// workspace offsets (in float units)
constexpr size_t WS_OUT1B = 0;                                     // N*16*HW bf16
constexpr size_t WS_OUT2B = WS_OUT1B + (size_t)NN * CMID * HW / 2; // N*64*HW bf16

// conv1 (256->16) + BN1 + ReLU via bf16 MFMA.
// Block: 256 thr (4 waves), tile = 64 px x 256 ci -> 16 c x 64 px.
__global__ __launch_bounds__(256) void k1(const float* __restrict__ x,
                                          const float* __restrict__ w1,
                                          const float* __restrict__ g1,
                                          const float* __restrict__ b1,
                                          const float* __restrict__ m1,
                                          const float* __restrict__ v1,
                                          __hip_bfloat16* __restrict__ out1b) {
  __shared__ __hip_bfloat16 Xb[64][264]; // [px][ci], 528B rows
  __shared__ __hip_bfloat16 Wb[16][264]; // [c][ci] folded w1*inv1
  int bid = blockIdx.x;                  // NN*49
  int n = bid / 49, hwb = (bid % 49) * 64;
  int tid = threadIdx.x;
  int l = tid & 63, w = tid >> 6;

  // stage Wb: thread t -> c = t>>4, k-range = (t&15)*16 .. +16
  {
    int c = tid >> 4, kb = (tid & 15) * 16;
    float inv = g1[c] / sqrtf(v1[c] + EPSB);
    const float* wp = w1 + c * CIN + kb;
#pragma unroll
    for (int j = 0; j < 16; ++j)
      Wb[c][kb + j] = __float2bfloat16(wp[j] * inv);
  }

  // stage Xb transposed: thread t -> px quad (t&15)*4, ci pair base (t>>4)*2
  {
    const float* xb = x + (size_t)n * CIN * HW + hwb;
    int pxq = (tid & 15) * 4;
    int cio = (tid >> 4) * 2;
#pragma unroll
    for (int p = 0; p < 8; ++p) {
      int ci = p * 32 + cio;
      f32x4 a = *reinterpret_cast<const f32x4*>(xb + (size_t)ci * HW + pxq);
      f32x4 b = *reinterpret_cast<const f32x4*>(xb + (size_t)(ci + 1) * HW + pxq);
#pragma unroll
      for (int j = 0; j < 4; ++j) {
        unsigned lo = (unsigned)__bfloat16_as_ushort(__float2bfloat16(a[j]));
        unsigned hi = (unsigned)__bfloat16_as_ushort(__float2bfloat16(b[j]));
        *reinterpret_cast<unsigned*>(&Xb[pxq + j][ci]) = lo | (hi << 16);
      }
    }
  }
  __syncthreads();

  // MFMA: A = Wb [c][k], B = Xb [k][px] (frag reads from [px][k] rows)
  int pix = 16 * w + (l & 15);
  f32x4 acc = (f32x4)(0.f);
#pragma unroll
  for (int kk = 0; kk < 8; ++kk) {
    int k0 = kk * 32 + (l >> 4) * 8;
    short8 afr = *reinterpret_cast<const short8*>(&Wb[l & 15][k0]);
    short8 bfr = *reinterpret_cast<const short8*>(&Xb[pix][k0]);
    acc = __builtin_amdgcn_mfma_f32_16x16x32_bf16(afr, bfr, acc, 0, 0, 0);
  }

  // epilogue: D row = c = (l>>4)*4 + j, col = pix  (bf16 stores)
#pragma unroll
  for (int j = 0; j < 4; ++j) {
    int c = (l >> 4) * 4 + j;
    float inv = g1[c] / sqrtf(v1[c] + EPSB);
    float val = acc[j] + (b1[c] - m1[c] * inv);
    out1b[((size_t)n * CMID + c) * HW + hwb + pix] = __float2bfloat16(fmaxf(val, 0.f));
  }
}

// 8-byte LDS load at 4-byte alignment -> ds_read2_b32 (1 LDS instr)
struct __attribute__((packed, aligned(4))) fpair { float lo, hi; };

__device__ __forceinline__ float bilin(const float* __restrict__ sI, float y, float x) {
  int iy = min((int)y, 55);
  int ix = min((int)x, 55);
  float ty = y - (float)iy;
  float tx = x - (float)ix;
  const float* r = sI + iy * 57 + ix;
  fpair ab = *reinterpret_cast<const fpair*>(r);       // a=r[0], b=r[1]
  fpair cd = *reinterpret_cast<const fpair*>(r + 57);  // c=r[57], d=r[58]
  float g1v = ab.lo * (1.f - ty) + cd.lo * ty;
  float g2v = ab.hi * (1.f - ty) + cd.hi * ty;
  return g1v * (1.f - tx) + g2v * tx;
}

// integral image (wave-parallel scans) + 4 boxes + BN2 + ReLU -> bf16.
__global__ __launch_bounds__(512) void k2(
    const __hip_bfloat16* __restrict__ out1b,
    const float* __restrict__ y_min, const float* __restrict__ y_max,
    const float* __restrict__ x_min, const float* __restrict__ x_max,
    const float* __restrict__ g2, const float* __restrict__ b2,
    const float* __restrict__ m2, const float* __restrict__ v2,
    __hip_bfloat16* __restrict__ out2b) {
  __shared__ float sI[57 * 57];
  int bid = blockIdx.x;            // NN*CMID = 512
  int n = bid >> 4, c = bid & 15;
  int tid = threadIdx.x;
  int lane = tid & 63, w = tid >> 6; // 8 waves

  if (tid < 57) { sI[tid] = 0.f; sI[tid * 57] = 0.f; }
  const __hip_bfloat16* src = out1b + ((size_t)n * CMID + c) * HW;
  if (tid < HW / 8) { // 392 vector loads of 8 px (56%8==0 -> same row)
    int p = tid * 8;
    int h = p / 56, wq = p - h * 56;
    short8 d = ((const short8*)src)[tid];
    const __hip_bfloat16* dp = (const __hip_bfloat16*)&d;
    float* dst = &sI[(h + 1) * 57 + wq + 1];
#pragma unroll
    for (int j = 0; j < 8; ++j) dst[j] = __bfloat162float(dp[j]);
  }
  __syncthreads();

  for (int r = w; r < 56; r += 8) {
    float* row = &sI[(r + 1) * 57 + 1];
    float vv = (lane < 56) ? row[lane] : 0.f;
#pragma unroll
    for (int d = 1; d < 64; d <<= 1) {
      float o = __shfl_up(vv, d, 64);
      if (lane >= d) vv += o;
    }
    if (lane < 56) row[lane] = vv;
  }
  __syncthreads();
  for (int cc = w; cc < 56; cc += 8) {
    float* col = &sI[57 + cc + 1];
    float vv = (lane < 56) ? col[lane * 57] : 0.f;
#pragma unroll
    for (int d = 1; d < 64; d <<= 1) {
      float o = __shfl_up(vv, d, 64);
      if (lane >= d) vv += o;
    }
    if (lane < 56) col[lane * 57] = vv;
  }
  __syncthreads();

  float pymn[NB], pymx[NB], pxmn[NB], pxmx[NB], pinv[NB], pbi[NB], prar[NB];
#pragma unroll
  for (int b = 0; b < NB; ++b) {
    int cb = c * NB + b;
    pymn[b] = y_min[cb]; pymx[b] = y_max[cb];
    pxmn[b] = x_min[cb]; pxmx[b] = x_max[cb];
    float inv = g2[cb] / sqrtf(v2[cb] + EPSB);
    pinv[b] = inv;
    pbi[b] = b2[cb] - m2[cb] * inv;
    prar[b] = 1.f / ((pymx[b] - pymn[b] + 1.f) * (pxmx[b] - pxmn[b] + 1.f));
  }
  __hip_bfloat16* dst0 = out2b + ((size_t)n * CBOX + c * NB) * HW;

  for (int p = tid; p < HW; p += 512) {
    int h = p / 56, wq = p - h * 56;
    float fh = (float)h, fw = (float)wq;
#pragma unroll
    for (int b = 0; b < NB; ++b) {
      float y1 = fminf(fmaxf(fh + pymn[b], 0.f), 56.f);
      float y2 = fminf(fmaxf(fh + pymx[b] + 1.f, 0.f), 56.f);
      float x1 = fminf(fmaxf(fw + pxmn[b], 0.f), 56.f);
      float x2 = fminf(fmaxf(fw + pxmx[b] + 1.f, 0.f), 56.f);
      float S = bilin(sI, y2, x2) - bilin(sI, y2, x1) - bilin(sI, y1, x2) + bilin(sI, y1, x1);
      float val = S * prar[b] * pinv[b] + pbi[b];
      dst0[(size_t)b * HW + p] = __float2bfloat16(fmaxf(val, 0.f));
    }
  }
}

// conv3 (64->256) via bf16 MFMA + BN3 + residual + ReLU.
__global__ __launch_bounds__(512) void k3(
    const __hip_bfloat16* __restrict__ out2b,
    const float* __restrict__ w3,
    const float* __restrict__ g3, const float* __restrict__ b3,
    const float* __restrict__ m3, const float* __restrict__ v3,
    const float* __restrict__ x, float* __restrict__ out) {
  __shared__ __hip_bfloat16 T[64][72]; // [pix][k], 144B rows
  int bid = blockIdx.x;                // NN*49
  int n = bid / 49, hwb = (bid % 49) * 64;
  int tid = threadIdx.x;
  int l = tid & 63, w = tid >> 6;

  {
    const __hip_bfloat16* srcp = out2b + ((size_t)n * CBOX + l) * HW + hwb + w * 8;
    short8 v = *reinterpret_cast<const short8*>(srcp);
    const __hip_bfloat16* vp = (const __hip_bfloat16*)&v;
#pragma unroll
    for (int i = 0; i < 8; ++i) T[w * 8 + i][l] = vp[i];
  }

  short8 afrag[2][2];
#pragma unroll
  for (int ot = 0; ot < 2; ++ot)
#pragma unroll
    for (int kh = 0; kh < 2; ++kh) {
      int o = w * 32 + ot * 16 + (l & 15);
      int k0 = kh * 32 + (l >> 4) * 8;
      const float* wp = w3 + o * CBOX + k0;
      union { short8 s; __hip_bfloat16 h[8]; } u;
#pragma unroll
      for (int j = 0; j < 8; ++j) u.h[j] = __float2bfloat16(wp[j]);
      afrag[ot][kh] = u.s;
    }

  __syncthreads();

  short8 bfrag[4][2];
#pragma unroll
  for (int pt = 0; pt < 4; ++pt)
#pragma unroll
    for (int kh = 0; kh < 2; ++kh) {
      int pix = pt * 16 + (l & 15);
      int k0 = kh * 32 + (l >> 4) * 8;
      bfrag[pt][kh] = *reinterpret_cast<const short8*>(&T[pix][k0]);
    }

  f32x4 acc[2][4];
#pragma unroll
  for (int ot = 0; ot < 2; ++ot)
#pragma unroll
    for (int pt = 0; pt < 4; ++pt) acc[ot][pt] = (f32x4)(0.f);

#pragma unroll
  for (int ot = 0; ot < 2; ++ot)
#pragma unroll
    for (int pt = 0; pt < 4; ++pt) {
      acc[ot][pt] = __builtin_amdgcn_mfma_f32_16x16x32_bf16(
          afrag[ot][0], bfrag[pt][0], acc[ot][pt], 0, 0, 0);
      acc[ot][pt] = __builtin_amdgcn_mfma_f32_16x16x32_bf16(
          afrag[ot][1], bfrag[pt][1], acc[ot][pt], 0, 0, 0);
    }

  size_t nbase = (size_t)n * COUT * HW + hwb;
#pragma unroll
  for (int ot = 0; ot < 2; ++ot) {
#pragma unroll
    for (int j = 0; j < 4; ++j) {
      int o = w * 32 + ot * 16 + (l >> 4) * 4 + j;
      float iv = g3[o] / sqrtf(v3[o] + EPSB);
      float bb = b3[o] - m3[o] * iv;
      size_t rowbase = nbase + (size_t)o * HW;
#pragma unroll
      for (int pt = 0; pt < 4; ++pt) {
        int pix = pt * 16 + (l & 15);
        float v = acc[ot][pt][j] * iv + bb + x[rowbase + pix];
        out[rowbase + pix] = fmaxf(v, 0.f);
      }
    }
  }
}

extern "C" void kernel_launch(void* const* d_in, const int* in_sizes, int n_in,
                              void* d_out, int out_size, void* d_ws, size_t ws_size,
                              hipStream_t stream) {
  const float* x   = (const float*)d_in[0];
  const float* w1  = (const float*)d_in[1];
  const float* g1  = (const float*)d_in[2];
  const float* b1  = (const float*)d_in[3];
  const float* m1  = (const float*)d_in[4];
  const float* v1  = (const float*)d_in[5];
  const float* ymn = (const float*)d_in[6];
  const float* ymx = (const float*)d_in[7];
  const float* xmn = (const float*)d_in[8];
  const float* xmx = (const float*)d_in[9];
  const float* g2  = (const float*)d_in[10];
  const float* b2  = (const float*)d_in[11];
  const float* m2  = (const float*)d_in[12];
  const float* v2  = (const float*)d_in[13];
  const float* w3  = (const float*)d_in[14];
  const float* g3  = (const float*)d_in[15];
  const float* b3  = (const float*)d_in[16];
  const float* m3  = (const float*)d_in[17];
  const float* v3  = (const float*)d_in[18];

  float* ws  = (float*)d_ws;
  float* out = (float*)d_out;
  __hip_bfloat16* out1b = (__hip_bfloat16*)(ws + WS_OUT1B);
  __hip_bfloat16* out2b = (__hip_bfloat16*)(ws + WS_OUT2B);

  k1<<<NN * 49, 256, 0, stream>>>(x, w1, g1, b1, m1, v1, out1b);
  k2<<<NN * CMID, 512, 0, stream>>>(out1b, ymn, ymx, xmn, xmx,
                                    g2, b2, m2, v2, out2b);
  k3<<<NN * 49, 512, 0, stream>>>(out2b, w3, g3, b3, m3, v3, x, out);
}